// Round 2
// baseline (9330.959 us; speedup 1.0000x reference)
//
#include <hip/hip_runtime.h>
#include <math.h>

#define E  512
#define NH 8
#define HDIM 64
#define FF 32
#define NL 3
#define NV 32000
#define NB 128
#define NT 16

// ---------------------------------------------------------------- pe table
__global__ void pe_init_kernel(float* __restrict__ pe) {
    int i = blockIdx.x;  // position 0..15
    for (int e = threadIdx.x; e < E; e += blockDim.x) {
        int k = e >> 1;
        double dv = exp((double)(2 * k) * (-log(10000.0) / (double)E));
        double arg = (double)i * dv;
        pe[i * E + e] = (e & 1) ? (float)cos(arg) : (float)sin(arg);
    }
}

// ------------------------------------------------------- tok_before row 0
__global__ void init_tok_kernel(float* __restrict__ tb, const float* __restrict__ emb) {
    int b = blockIdx.x;
    for (int e = threadIdx.x; e < E; e += blockDim.x)
        tb[(size_t)b * E + e] = emb[(size_t)1 * E + e];  // SOS = 1
}

// ------------------------------------------- C[M,N] = A[M,K] @ W[N,K]^T + bias
// Tile: (RREP*64) x 128, BK=16, 256 threads, each thread RREP*4 x 8 outputs.
// Requires: M % (RREP*64) == 0, N % 128 == 0, K % 16 == 0. No bounds checks.
template<int RREP>
__global__ __launch_bounds__(256) void gemm_tile_kernel(
    const float* __restrict__ A, const float* __restrict__ W,
    const float* __restrict__ bias, float* __restrict__ C,
    int N, int K)
{
    constexpr int AW = RREP * 64 + 4;   // +4 pad: staging writes 2-way max
    __shared__ float As[16][AW];        // As[k][m]
    __shared__ float Bs[16][132];       // Bs[k][n]
    const int tid = threadIdx.x;
    const int m0 = blockIdx.y * (RREP * 64);
    const int n0 = blockIdx.x * 128;
    const int tx = tid & 15;            // output col group
    const int ty = tid >> 4;            // output row group
    const int r0 = tid >> 2;            // staging row 0..63
    const int c0 = (tid & 3) << 2;      // staging col 0,4,8,12

    const float* Ap0 = A + (size_t)(m0 + r0) * K + c0;
    const float* Ap1 = A + (size_t)(m0 + r0 + 64) * K + c0;
    const float* Wp0 = W + (size_t)(n0 + r0) * K + c0;
    const float* Wp1 = W + (size_t)(n0 + r0 + 64) * K + c0;

    float4 pa0, pa1, pb0, pb1;
    pa0 = *(const float4*)Ap0;
    if constexpr (RREP == 2) pa1 = *(const float4*)Ap1;
    pb0 = *(const float4*)Wp0;
    pb1 = *(const float4*)Wp1;

    float acc[RREP][2][4][4] = {};
    const int nkt = K >> 4;
    for (int kt = 0; kt < nkt; ++kt) {
        __syncthreads();
        As[c0 + 0][r0] = pa0.x; As[c0 + 1][r0] = pa0.y;
        As[c0 + 2][r0] = pa0.z; As[c0 + 3][r0] = pa0.w;
        if constexpr (RREP == 2) {
            As[c0 + 0][r0 + 64] = pa1.x; As[c0 + 1][r0 + 64] = pa1.y;
            As[c0 + 2][r0 + 64] = pa1.z; As[c0 + 3][r0 + 64] = pa1.w;
        }
        Bs[c0 + 0][r0] = pb0.x; Bs[c0 + 1][r0] = pb0.y;
        Bs[c0 + 2][r0] = pb0.z; Bs[c0 + 3][r0] = pb0.w;
        Bs[c0 + 0][r0 + 64] = pb1.x; Bs[c0 + 1][r0 + 64] = pb1.y;
        Bs[c0 + 2][r0 + 64] = pb1.z; Bs[c0 + 3][r0 + 64] = pb1.w;
        __syncthreads();
        if (kt + 1 < nkt) {
            const int off = 16 * (kt + 1);
            pa0 = *(const float4*)(Ap0 + off);
            if constexpr (RREP == 2) pa1 = *(const float4*)(Ap1 + off);
            pb0 = *(const float4*)(Wp0 + off);
            pb1 = *(const float4*)(Wp1 + off);
        }
#pragma unroll
        for (int k = 0; k < 16; ++k) {
            const float4 b0 = *(const float4*)&Bs[k][tx * 4];
            const float4 b1 = *(const float4*)&Bs[k][64 + tx * 4];
            const float br[8] = {b0.x, b0.y, b0.z, b0.w, b1.x, b1.y, b1.z, b1.w};
            float ar[RREP * 4];
            const float4 a0 = *(const float4*)&As[k][ty * 4];
            ar[0] = a0.x; ar[1] = a0.y; ar[2] = a0.z; ar[3] = a0.w;
            if constexpr (RREP == 2) {
                const float4 a1 = *(const float4*)&As[k][64 + ty * 4];
                ar[4] = a1.x; ar[5] = a1.y; ar[6] = a1.z; ar[7] = a1.w;
            }
#pragma unroll
            for (int ri = 0; ri < RREP; ++ri)
#pragma unroll
                for (int i = 0; i < 4; ++i)
#pragma unroll
                    for (int rj = 0; rj < 2; ++rj)
#pragma unroll
                        for (int j = 0; j < 4; ++j)
                            acc[ri][rj][i][j] += ar[ri * 4 + i] * br[rj * 4 + j];
        }
    }
#pragma unroll
    for (int ri = 0; ri < RREP; ++ri)
#pragma unroll
        for (int i = 0; i < 4; ++i) {
            const int m = m0 + ri * 64 + ty * 4 + i;
#pragma unroll
            for (int rj = 0; rj < 2; ++rj) {
                const int n = n0 + rj * 64 + tx * 4;
                const float4 bv = *(const float4*)&bias[n];
                float4 o;
                o.x = acc[ri][rj][i][0] + bv.x;
                o.y = acc[ri][rj][i][1] + bv.y;
                o.z = acc[ri][rj][i][2] + bv.z;
                o.w = acc[ri][rj][i][3] + bv.w;
                *(float4*)&C[(size_t)m * N + n] = o;
            }
        }
}

// -------------------------------------------------------- self attention
// qkv layout: [(s*NB+b)*3E + {0|E|2E} + h*64 + d]. grid = NB*NH, block = 128.
__global__ __launch_bounds__(128) void attn_kernel(
    const float* __restrict__ qkv, float* __restrict__ o, int S)
{
    const int b = blockIdx.x >> 3;
    const int h = blockIdx.x & 7;
    __shared__ float Ks[16][64];
    __shared__ float Vs[16][64];
    const int tid = threadIdx.x;
    for (int idx = tid; idx < S * 64; idx += 128) {
        int s = idx >> 6, d = idx & 63;
        size_t base = ((size_t)(s * NB + b)) * (3 * E) + h * 64 + d;
        Ks[s][d] = qkv[base + E];
        Vs[s][d] = qkv[base + 2 * E];
    }
    __syncthreads();
    const int wid = tid >> 6, lane = tid & 63;
    for (int qi = wid; qi < S; qi += 2) {
        float qd = qkv[((size_t)(qi * NB + b)) * (3 * E) + h * 64 + lane];
        float sc[16];
#pragma unroll
        for (int ki = 0; ki < 16; ++ki) {
            float p = 0.f;
            if (ki < S) {
                p = qd * Ks[ki][lane];
#pragma unroll
                for (int off = 32; off; off >>= 1) p += __shfl_xor(p, off);
                p *= 0.125f;  // 1/sqrt(64)
            }
            sc[ki] = p;
        }
        float m = -1e30f;
#pragma unroll
        for (int ki = 0; ki < 16; ++ki) if (ki < S) m = fmaxf(m, sc[ki]);
        float sum = 0.f;
#pragma unroll
        for (int ki = 0; ki < 16; ++ki) if (ki < S) { sc[ki] = expf(sc[ki] - m); sum += sc[ki]; }
        float inv = 1.0f / sum;
        float acc = 0.f;
#pragma unroll
        for (int ki = 0; ki < 16; ++ki) if (ki < S) acc += sc[ki] * Vs[ki][lane];
        o[((size_t)(qi * NB + b)) * E + h * 64 + lane] = acc * inv;
    }
}

// ------------------------- x = LN(LN(xin + y; g0,b0) + ca; g1,b1), row-wise
__global__ __launch_bounds__(256) void lnln_kernel(
    const float* __restrict__ xin, const float* __restrict__ y,
    const float* __restrict__ ca,
    const float* __restrict__ g0, const float* __restrict__ b0,
    const float* __restrict__ g1, const float* __restrict__ b1,
    float* __restrict__ xout, int rows)
{
    const int wid = threadIdx.x >> 6, lane = threadIdx.x & 63;
    const int row = blockIdx.x * 4 + wid;
    if (row >= rows) return;
    const float* xr = xin + (size_t)row * E;
    const float* yr = y + (size_t)row * E;
    const float* cr = ca + (size_t)(row & (NB - 1)) * E;
    float v[8];
    float s = 0.f;
#pragma unroll
    for (int j = 0; j < 8; ++j) { int e = j * 64 + lane; v[j] = xr[e] + yr[e]; s += v[j]; }
#pragma unroll
    for (int off = 32; off; off >>= 1) s += __shfl_xor(s, off);
    float mean = s * (1.0f / E);
    float vs = 0.f;
#pragma unroll
    for (int j = 0; j < 8; ++j) { float d = v[j] - mean; vs += d * d; }
#pragma unroll
    for (int off = 32; off; off >>= 1) vs += __shfl_xor(vs, off);
    float rstd = rsqrtf(vs * (1.0f / E) + 1e-5f);
#pragma unroll
    for (int j = 0; j < 8; ++j) {
        int e = j * 64 + lane;
        v[j] = (v[j] - mean) * rstd * g0[e] + b0[e] + cr[e];
    }
    // second LN
    s = 0.f;
#pragma unroll
    for (int j = 0; j < 8; ++j) s += v[j];
#pragma unroll
    for (int off = 32; off; off >>= 1) s += __shfl_xor(s, off);
    mean = s * (1.0f / E);
    vs = 0.f;
#pragma unroll
    for (int j = 0; j < 8; ++j) { float d = v[j] - mean; vs += d * d; }
#pragma unroll
    for (int off = 32; off; off >>= 1) vs += __shfl_xor(vs, off);
    rstd = rsqrtf(vs * (1.0f / E) + 1e-5f);
#pragma unroll
    for (int j = 0; j < 8; ++j) {
        int e = j * 64 + lane;
        xout[(size_t)row * E + e] = (v[j] - mean) * rstd * g1[e] + b1[e];
    }
}

// ---------- fused FFN: x = LN(x + relu(x@W1^T+b1)@W2^T+b2; g2,bb2), wave/row
__global__ __launch_bounds__(256) void ffn_kernel(
    const float* __restrict__ x,
    const float* __restrict__ w1, const float* __restrict__ b1,
    const float* __restrict__ w2, const float* __restrict__ b2,
    const float* __restrict__ g2, const float* __restrict__ bb2,
    float* __restrict__ xout, int rows)
{
    const int wid = threadIdx.x >> 6, lane = threadIdx.x & 63;
    const int row = blockIdx.x * 4 + wid;
    if (row >= rows) return;
    const float* xr = x + (size_t)row * E;
    float v[8];
#pragma unroll
    for (int j = 0; j < 8; ++j) v[j] = xr[j * 64 + lane];
    float h[FF];
#pragma unroll
    for (int f = 0; f < FF; ++f) {
        float p = 0.f;
#pragma unroll
        for (int j = 0; j < 8; ++j) p += v[j] * w1[(size_t)f * E + j * 64 + lane];
#pragma unroll
        for (int off = 32; off; off >>= 1) p += __shfl_xor(p, off);
        h[f] = fmaxf(p + b1[f], 0.f);
    }
    float o[8];
#pragma unroll
    for (int j = 0; j < 8; ++j) {
        int e = j * 64 + lane;
        float acc = b2[e];
#pragma unroll
        for (int f4 = 0; f4 < FF / 4; ++f4) {
            float4 w4 = *(const float4*)&w2[(size_t)e * FF + f4 * 4];
            acc += h[f4 * 4 + 0] * w4.x + h[f4 * 4 + 1] * w4.y +
                   h[f4 * 4 + 2] * w4.z + h[f4 * 4 + 3] * w4.w;
        }
        o[j] = v[j] + acc;  // residual
    }
    float s = 0.f;
#pragma unroll
    for (int j = 0; j < 8; ++j) s += o[j];
#pragma unroll
    for (int off = 32; off; off >>= 1) s += __shfl_xor(s, off);
    float mean = s * (1.0f / E);
    float vs = 0.f;
#pragma unroll
    for (int j = 0; j < 8; ++j) { float d = o[j] - mean; vs += d * d; }
#pragma unroll
    for (int off = 32; off; off >>= 1) vs += __shfl_xor(vs, off);
    float rstd = rsqrtf(vs * (1.0f / E) + 1e-5f);
#pragma unroll
    for (int j = 0; j < 8; ++j) {
        int e = j * 64 + lane;
        xout[(size_t)row * E + e] = (o[j] - mean) * rstd * g2[e] + bb2[e];
    }
}

// ------- softmax over V per row + argmax token + append emb[tok]+pe row
__global__ __launch_bounds__(256) void softmax_kernel(
    float* __restrict__ probs,          // logits in, probs out (b*NV rows)
    float* __restrict__ tok_out,        // d_out tokens area
    const float* __restrict__ emb,
    const float* __restrict__ pe_row,   // pe + step*E
    float* __restrict__ tb_new,         // tok_before + S*NB*E
    int step)
{
    const int b = blockIdx.x, t = threadIdx.x;
    float* L = probs + (size_t)b * NV;
    float vmax = -1e30f; int imax = 0;
    for (int idx = t; idx < NV; idx += 256) {
        float val = L[idx];
        if (val > vmax) { vmax = val; imax = idx; }
    }
    __shared__ float sv[256];
    __shared__ int si[256];
    sv[t] = vmax; si[t] = imax;
    __syncthreads();
    for (int off = 128; off; off >>= 1) {
        if (t < off) {
            if (sv[t + off] > sv[t] || (sv[t + off] == sv[t] && si[t + off] < si[t])) {
                sv[t] = sv[t + off]; si[t] = si[t + off];
            }
        }
        __syncthreads();
    }
    const float m = sv[0];
    const int tok = si[0];
    __syncthreads();
    float psum = 0.f;
    for (int idx = t; idx < NV; idx += 256) psum += expf(L[idx] - m);
    sv[t] = psum;
    __syncthreads();
    for (int off = 128; off; off >>= 1) {
        if (t < off) sv[t] += sv[t + off];
        __syncthreads();
    }
    const float inv = 1.0f / sv[0];
    for (int idx = t; idx < NV; idx += 256) L[idx] = expf(L[idx] - m) * inv;
    if (t == 0) tok_out[(size_t)b * NT + step] = (float)tok;
    for (int e = t; e < E; e += 256)
        tb_new[(size_t)b * E + e] = emb[(size_t)tok * E + e] + pe_row[e];
}

// ================================================================ host
extern "C" void kernel_launch(void* const* d_in, const int* in_sizes, int n_in,
                              void* d_out, int out_size, void* d_ws, size_t ws_size,
                              hipStream_t stream) {
    const float* cur_room = (const float*)d_in[0];
    const float* emb      = (const float*)d_in[1];
    const float* sa_in_w  = (const float*)d_in[2];
    const float* sa_in_b  = (const float*)d_in[3];
    const float* sa_out_w = (const float*)d_in[4];
    const float* sa_out_b = (const float*)d_in[5];
    const float* ca_in_w  = (const float*)d_in[6];
    const float* ca_in_b  = (const float*)d_in[7];
    const float* ca_out_w = (const float*)d_in[8];
    const float* ca_out_b = (const float*)d_in[9];
    const float* ff1_w    = (const float*)d_in[10];
    const float* ff1_b    = (const float*)d_in[11];
    const float* ff2_w    = (const float*)d_in[12];
    const float* ff2_b    = (const float*)d_in[13];
    const float* ln_g     = (const float*)d_in[14];
    const float* ln_b     = (const float*)d_in[15];
    const float* out_w    = (const float*)d_in[16];
    const float* out_b    = (const float*)d_in[17];
    float* out = (float*)d_out;

    float* ws = (float*)d_ws;
    float* pe       = ws;                                  // 16*E
    float* ca_const = pe + 16 * E;                         // NL*NB*E
    float* tokb     = ca_const + (size_t)NL * NB * E;      // 17*NB*E
    float* x        = tokb + (size_t)17 * NB * E;          // 16*NB*E
    float* qkv0     = x + (size_t)16 * NB * E;             // 16*NB*3E (layer-0 cache)
    float* qkvb     = qkv0 + (size_t)16 * NB * 3 * E;      // 16*NB*3E
    float* attn_o   = qkvb + (size_t)16 * NB * 3 * E;      // 16*NB*E
    float* ybuf     = attn_o + (size_t)16 * NB * E;        // 16*NB*E
    float* hv       = ybuf + (size_t)16 * NB * E;          // NB*E

    pe_init_kernel<<<16, 256, 0, stream>>>(pe);
    init_tok_kernel<<<NB, 256, 0, stream>>>(tokb, emb);

    // cross-attention constants: ca_const[l] = (hx @ Wv^T + bv) @ Wout^T + bout
    // (KV length is 1 -> softmax == 1 -> attention output is the V projection)
    for (int l = 0; l < NL; ++l) {
        const float* wv = ca_in_w + ((size_t)l * 3 * E + 2 * E) * E;
        const float* bv = ca_in_b + (size_t)l * 3 * E + 2 * E;
        gemm_tile_kernel<1><<<dim3(E / 128, 2), 256, 0, stream>>>(
            cur_room, wv, bv, hv, E, E);
        gemm_tile_kernel<1><<<dim3(E / 128, 2), 256, 0, stream>>>(
            hv, ca_out_w + (size_t)l * E * E, ca_out_b + (size_t)l * E,
            ca_const + (size_t)l * NB * E, E, E);
    }

    for (int i = 0; i < NT; ++i) {
        const int S = i + 1;
        const int M = S * NB;
        // layer-0 qkv is incremental: rows for positions < i are unchanged
        gemm_tile_kernel<1><<<dim3(3 * E / 128, 2), 256, 0, stream>>>(
            tokb + (size_t)i * NB * E, sa_in_w, sa_in_b,
            qkv0 + (size_t)i * NB * 3 * E, 3 * E, E);
        for (int l = 0; l < NL; ++l) {
            const float* xin = (l == 0) ? tokb : x;
            const float* qkv_l;
            if (l == 0) {
                qkv_l = qkv0;
            } else {
                if (S == 1) {
                    gemm_tile_kernel<1><<<dim3(3 * E / 128, 2), 256, 0, stream>>>(
                        xin, sa_in_w + (size_t)l * 3 * E * E, sa_in_b + (size_t)l * 3 * E,
                        qkvb, 3 * E, E);
                } else {
                    gemm_tile_kernel<2><<<dim3(3 * E / 128, M / 128), 256, 0, stream>>>(
                        xin, sa_in_w + (size_t)l * 3 * E * E, sa_in_b + (size_t)l * 3 * E,
                        qkvb, 3 * E, E);
                }
                qkv_l = qkvb;
            }
            attn_kernel<<<NB * NH, 128, 0, stream>>>(qkv_l, attn_o, S);
            if (S == 1) {
                gemm_tile_kernel<1><<<dim3(E / 128, 2), 256, 0, stream>>>(
                    attn_o, sa_out_w + (size_t)l * E * E, sa_out_b + (size_t)l * E,
                    ybuf, E, E);
            } else {
                gemm_tile_kernel<2><<<dim3(E / 128, M / 128), 256, 0, stream>>>(
                    attn_o, sa_out_w + (size_t)l * E * E, sa_out_b + (size_t)l * E,
                    ybuf, E, E);
            }
            lnln_kernel<<<S * 32, 256, 0, stream>>>(
                xin, ybuf, ca_const + (size_t)l * NB * E,
                ln_g + (size_t)(l * 3 + 0) * E, ln_b + (size_t)(l * 3 + 0) * E,
                ln_g + (size_t)(l * 3 + 1) * E, ln_b + (size_t)(l * 3 + 1) * E,
                x, M);
            ffn_kernel<<<S * 32, 256, 0, stream>>>(
                x, ff1_w + (size_t)l * FF * E, ff1_b + (size_t)l * FF,
                ff2_w + (size_t)l * E * FF, ff2_b + (size_t)l * E,
                ln_g + (size_t)(l * 3 + 2) * E, ln_b + (size_t)(l * 3 + 2) * E,
                x, M);
        }
        float* probs = out + 2048 + (size_t)i * NB * NV;
        // vocab projection of the LAST position only (M = 128), 64-row tiles
        gemm_tile_kernel<1><<<dim3(NV / 128, 2), 256, 0, stream>>>(
            x + (size_t)(S - 1) * NB * E, out_w, out_b, probs, NV, E);
        softmax_kernel<<<NB, 256, 0, stream>>>(
            probs, out, emb, pe + (size_t)i * E, tokb + (size_t)S * NB * E, i);
    }
}

// Round 3
// 8555.341 us; speedup vs baseline: 1.0907x; 1.0907x over previous
//
#include <hip/hip_runtime.h>
#include <math.h>

#define E  512
#define NH 8
#define HDIM 64
#define FF 32
#define NL 3
#define NV 32000
#define NB 128
#define NT 16

// ---------------------------------------------------------------- pe table
__global__ void pe_init_kernel(float* __restrict__ pe) {
    int i = blockIdx.x;  // position 0..15
    for (int e = threadIdx.x; e < E; e += blockDim.x) {
        int k = e >> 1;
        double dv = exp((double)(2 * k) * (-log(10000.0) / (double)E));
        double arg = (double)i * dv;
        pe[i * E + e] = (e & 1) ? (float)cos(arg) : (float)sin(arg);
    }
}

// ------------------------------------------------------- tok_before row 0
__global__ void init_tok_kernel(float* __restrict__ tb, const float* __restrict__ emb) {
    int b = blockIdx.x;
    for (int e = threadIdx.x; e < E; e += blockDim.x)
        tb[(size_t)b * E + e] = emb[(size_t)1 * E + e];  // SOS = 1
}

// ---------------------------------------------------------------- GEMM
// C_partial[z] = A[M,KC slice] @ W[N,KC slice]^T  (+bias if ADD_BIAS)
// Tile 64x128, 128 threads, 8x8 per thread. Requires M%64==0, N%128==0,
// KC%16==0. Partial z writes to C + z*CS. Bias only meaningful when
// gridDim.z==1 (unsplit).
template<bool ADD_BIAS>
__global__ __launch_bounds__(128) void gemm64x128_kernel(
    const float* __restrict__ A, const float* __restrict__ W,
    const float* __restrict__ bias, float* __restrict__ C,
    int N, int K, int KC, size_t CS)
{
    __shared__ float As[16][68];    // [k][m]
    __shared__ float Bs[16][132];   // [k][n]
    const int tid = threadIdx.x;
    const int m0 = blockIdx.y * 64;
    const int n0 = blockIdx.x * 128;
    const int kc0 = blockIdx.z * KC;
    const int tx = tid & 15, ty = tid >> 4;
    const int arow = tid >> 1, acol = (tid & 1) * 8;

    const float* Ap = A + (size_t)(m0 + arow) * K + kc0 + acol;
    const float* Wp = W + (size_t)(n0 + tid) * K + kc0;

    float4 pa0 = *(const float4*)Ap;
    float4 pa1 = *(const float4*)(Ap + 4);
    float4 pw0 = *(const float4*)Wp;
    float4 pw1 = *(const float4*)(Wp + 4);
    float4 pw2 = *(const float4*)(Wp + 8);
    float4 pw3 = *(const float4*)(Wp + 12);

    float acc[8][8] = {};
    const int nkt = KC >> 4;
    for (int kt = 0; kt < nkt; ++kt) {
        __syncthreads();
        As[acol + 0][arow] = pa0.x; As[acol + 1][arow] = pa0.y;
        As[acol + 2][arow] = pa0.z; As[acol + 3][arow] = pa0.w;
        As[acol + 4][arow] = pa1.x; As[acol + 5][arow] = pa1.y;
        As[acol + 6][arow] = pa1.z; As[acol + 7][arow] = pa1.w;
        Bs[ 0][tid] = pw0.x; Bs[ 1][tid] = pw0.y; Bs[ 2][tid] = pw0.z; Bs[ 3][tid] = pw0.w;
        Bs[ 4][tid] = pw1.x; Bs[ 5][tid] = pw1.y; Bs[ 6][tid] = pw1.z; Bs[ 7][tid] = pw1.w;
        Bs[ 8][tid] = pw2.x; Bs[ 9][tid] = pw2.y; Bs[10][tid] = pw2.z; Bs[11][tid] = pw2.w;
        Bs[12][tid] = pw3.x; Bs[13][tid] = pw3.y; Bs[14][tid] = pw3.z; Bs[15][tid] = pw3.w;
        __syncthreads();
        if (kt + 1 < nkt) {
            const int off = 16 * (kt + 1);
            pa0 = *(const float4*)(Ap + off);
            pa1 = *(const float4*)(Ap + off + 4);
            pw0 = *(const float4*)(Wp + off);
            pw1 = *(const float4*)(Wp + off + 4);
            pw2 = *(const float4*)(Wp + off + 8);
            pw3 = *(const float4*)(Wp + off + 12);
        }
#pragma unroll
        for (int k = 0; k < 16; ++k) {
            float a[8], b[8];
            *(float4*)&a[0] = *(const float4*)&As[k][ty * 4];
            *(float4*)&a[4] = *(const float4*)&As[k][32 + ty * 4];
            *(float4*)&b[0] = *(const float4*)&Bs[k][tx * 4];
            *(float4*)&b[4] = *(const float4*)&Bs[k][64 + tx * 4];
#pragma unroll
            for (int i = 0; i < 8; ++i)
#pragma unroll
                for (int j = 0; j < 8; ++j)
                    acc[i][j] += a[i] * b[j];
        }
    }
    float* Co = C + (size_t)blockIdx.z * CS;
#pragma unroll
    for (int half = 0; half < 2; ++half)
#pragma unroll
        for (int i = 0; i < 4; ++i) {
            const int m = m0 + half * 32 + ty * 4 + i;
#pragma unroll
            for (int cj = 0; cj < 2; ++cj) {
                const int n = n0 + cj * 64 + tx * 4;
                float4 o;
                o.x = acc[half * 4 + i][cj * 4 + 0];
                o.y = acc[half * 4 + i][cj * 4 + 1];
                o.z = acc[half * 4 + i][cj * 4 + 2];
                o.w = acc[half * 4 + i][cj * 4 + 3];
                if (ADD_BIAS) {
                    const float4 bv = *(const float4*)&bias[n];
                    o.x += bv.x; o.y += bv.y; o.z += bv.z; o.w += bv.w;
                }
                *(float4*)&Co[(size_t)m * N + n] = o;
            }
        }
}

// -------------------------------------------------------- self attention
// qkv partials: qkv + p*QS, row layout [(s*NB+b)*3E + {0|E|2E} + h*64 + d].
// Sums pcount partials + bias while staging. grid = NB*NH, block = 128.
__global__ __launch_bounds__(128) void attn_kernel(
    const float* __restrict__ qkv, size_t QS, int pcount,
    const float* __restrict__ bias,   // sa_in_b + l*3E
    float* __restrict__ o, int S)
{
    const int b = blockIdx.x >> 3;
    const int h = blockIdx.x & 7;
    __shared__ float Ks[16][64];
    __shared__ float Vs[16][64];
    const int tid = threadIdx.x;
    for (int idx = tid; idx < S * 64; idx += 128) {
        int s = idx >> 6, d = idx & 63;
        size_t base = ((size_t)(s * NB + b)) * (3 * E) + h * 64 + d;
        float kk = bias[E + h * 64 + d];
        float vv = bias[2 * E + h * 64 + d];
        for (int p = 0; p < pcount; ++p) {
            kk += qkv[(size_t)p * QS + base + E];
            vv += qkv[(size_t)p * QS + base + 2 * E];
        }
        Ks[s][d] = kk;
        Vs[s][d] = vv;
    }
    __syncthreads();
    const int wid = tid >> 6, lane = tid & 63;
    const float bq = bias[h * 64 + lane];
    for (int qi = wid; qi < S; qi += 2) {
        size_t qbase = ((size_t)(qi * NB + b)) * (3 * E) + h * 64 + lane;
        float qd = bq;
        for (int p = 0; p < pcount; ++p) qd += qkv[(size_t)p * QS + qbase];
        float sc[16];
#pragma unroll
        for (int ki = 0; ki < 16; ++ki) {
            float p = 0.f;
            if (ki < S) {
                p = qd * Ks[ki][lane];
#pragma unroll
                for (int off = 32; off; off >>= 1) p += __shfl_xor(p, off);
                p *= 0.125f;  // 1/sqrt(64)
            }
            sc[ki] = p;
        }
        float m = -1e30f;
#pragma unroll
        for (int ki = 0; ki < 16; ++ki) if (ki < S) m = fmaxf(m, sc[ki]);
        float sum = 0.f;
#pragma unroll
        for (int ki = 0; ki < 16; ++ki) if (ki < S) { sc[ki] = expf(sc[ki] - m); sum += sc[ki]; }
        float inv = 1.0f / sum;
        float acc = 0.f;
#pragma unroll
        for (int ki = 0; ki < 16; ++ki) if (ki < S) acc += sc[ki] * Vs[ki][lane];
        o[((size_t)(qi * NB + b)) * E + h * 64 + lane] = acc * inv;
    }
}

// ---- fused epilogue: y = sum(ypartials)+ob; x1 = LN0(xin+y); x2 = LN1(x1+ca)
//      x = LN2(x2 + FFN(x2)).  One wave per row, 4 rows per block.
__global__ __launch_bounds__(256) void epilogue_kernel(
    const float* __restrict__ xin,
    const float* __restrict__ yp, size_t YS, int pcount,
    const float* __restrict__ ob,
    const float* __restrict__ ca,
    const float* __restrict__ g0, const float* __restrict__ b0,
    const float* __restrict__ g1, const float* __restrict__ b1,
    const float* __restrict__ w1, const float* __restrict__ b1f,
    const float* __restrict__ w2, const float* __restrict__ b2f,
    const float* __restrict__ g2, const float* __restrict__ bb2,
    float* __restrict__ xout, int rows)
{
    const int wid = threadIdx.x >> 6, lane = threadIdx.x & 63;
    const int row = blockIdx.x * 4 + wid;
    if (row >= rows) return;
    const float* xr = xin + (size_t)row * E;
    const float* cr = ca + (size_t)(row & (NB - 1)) * E;
    float v[8];
    float s = 0.f;
#pragma unroll
    for (int j = 0; j < 8; ++j) {
        int e = j * 64 + lane;
        float y = xr[e] + ob[e];
        for (int p = 0; p < pcount; ++p) y += yp[(size_t)p * YS + (size_t)row * E + e];
        v[j] = y; s += y;
    }
#pragma unroll
    for (int off = 32; off; off >>= 1) s += __shfl_xor(s, off);
    float mean = s * (1.0f / E);
    float vs = 0.f;
#pragma unroll
    for (int j = 0; j < 8; ++j) { float d = v[j] - mean; vs += d * d; }
#pragma unroll
    for (int off = 32; off; off >>= 1) vs += __shfl_xor(vs, off);
    float rstd = rsqrtf(vs * (1.0f / E) + 1e-5f);
#pragma unroll
    for (int j = 0; j < 8; ++j) {
        int e = j * 64 + lane;
        v[j] = (v[j] - mean) * rstd * g0[e] + b0[e] + cr[e];
    }
    // LN1
    s = 0.f;
#pragma unroll
    for (int j = 0; j < 8; ++j) s += v[j];
#pragma unroll
    for (int off = 32; off; off >>= 1) s += __shfl_xor(s, off);
    mean = s * (1.0f / E);
    vs = 0.f;
#pragma unroll
    for (int j = 0; j < 8; ++j) { float d = v[j] - mean; vs += d * d; }
#pragma unroll
    for (int off = 32; off; off >>= 1) vs += __shfl_xor(vs, off);
    rstd = rsqrtf(vs * (1.0f / E) + 1e-5f);
#pragma unroll
    for (int j = 0; j < 8; ++j) {
        int e = j * 64 + lane;
        v[j] = (v[j] - mean) * rstd * g1[e] + b1[e];
    }
    // FFN
    float h[FF];
#pragma unroll
    for (int f = 0; f < FF; ++f) {
        float p = 0.f;
#pragma unroll
        for (int j = 0; j < 8; ++j) p += v[j] * w1[(size_t)f * E + j * 64 + lane];
#pragma unroll
        for (int off = 32; off; off >>= 1) p += __shfl_xor(p, off);
        h[f] = fmaxf(p + b1f[f], 0.f);
    }
    float o[8];
#pragma unroll
    for (int j = 0; j < 8; ++j) {
        int e = j * 64 + lane;
        float acc = b2f[e];
#pragma unroll
        for (int f4 = 0; f4 < FF / 4; ++f4) {
            float4 w4 = *(const float4*)&w2[(size_t)e * FF + f4 * 4];
            acc += h[f4 * 4 + 0] * w4.x + h[f4 * 4 + 1] * w4.y +
                   h[f4 * 4 + 2] * w4.z + h[f4 * 4 + 3] * w4.w;
        }
        o[j] = v[j] + acc;
    }
    // LN2
    s = 0.f;
#pragma unroll
    for (int j = 0; j < 8; ++j) s += o[j];
#pragma unroll
    for (int off = 32; off; off >>= 1) s += __shfl_xor(s, off);
    mean = s * (1.0f / E);
    vs = 0.f;
#pragma unroll
    for (int j = 0; j < 8; ++j) { float d = o[j] - mean; vs += d * d; }
#pragma unroll
    for (int off = 32; off; off >>= 1) vs += __shfl_xor(vs, off);
    rstd = rsqrtf(vs * (1.0f / E) + 1e-5f);
#pragma unroll
    for (int j = 0; j < 8; ++j) {
        int e = j * 64 + lane;
        xout[(size_t)row * E + e] = (o[j] - mean) * rstd * g2[e] + bb2[e];
    }
}

// ------- softmax over V per row + argmax token + append emb[tok]+pe row
__global__ __launch_bounds__(256) void softmax_kernel(
    float* __restrict__ probs, float* __restrict__ tok_out,
    const float* __restrict__ emb, const float* __restrict__ pe_row,
    float* __restrict__ tb_new, int step)
{
    const int b = blockIdx.x, t = threadIdx.x;
    float* L = probs + (size_t)b * NV;
    float vmax = -1e30f; int imax = 0;
    for (int idx = t; idx < NV; idx += 256) {
        float val = L[idx];
        if (val > vmax) { vmax = val; imax = idx; }
    }
    __shared__ float sv[256];
    __shared__ int si[256];
    sv[t] = vmax; si[t] = imax;
    __syncthreads();
    for (int off = 128; off; off >>= 1) {
        if (t < off) {
            if (sv[t + off] > sv[t] || (sv[t + off] == sv[t] && si[t + off] < si[t])) {
                sv[t] = sv[t + off]; si[t] = si[t + off];
            }
        }
        __syncthreads();
    }
    const float m = sv[0];
    const int tok = si[0];
    __syncthreads();
    float psum = 0.f;
    for (int idx = t; idx < NV; idx += 256) psum += expf(L[idx] - m);
    sv[t] = psum;
    __syncthreads();
    for (int off = 128; off; off >>= 1) {
        if (t < off) sv[t] += sv[t + off];
        __syncthreads();
    }
    const float inv = 1.0f / sv[0];
    for (int idx = t; idx < NV; idx += 256) L[idx] = expf(L[idx] - m) * inv;
    if (t == 0) tok_out[(size_t)b * NT + step] = (float)tok;
    for (int e = t; e < E; e += 256)
        tb_new[(size_t)b * E + e] = emb[(size_t)tok * E + e] + pe_row[e];
}

// ================================================================ host
extern "C" void kernel_launch(void* const* d_in, const int* in_sizes, int n_in,
                              void* d_out, int out_size, void* d_ws, size_t ws_size,
                              hipStream_t stream) {
    const float* cur_room = (const float*)d_in[0];
    const float* emb      = (const float*)d_in[1];
    const float* sa_in_w  = (const float*)d_in[2];
    const float* sa_in_b  = (const float*)d_in[3];
    const float* sa_out_w = (const float*)d_in[4];
    const float* sa_out_b = (const float*)d_in[5];
    const float* ca_in_w  = (const float*)d_in[6];
    const float* ca_in_b  = (const float*)d_in[7];
    const float* ca_out_w = (const float*)d_in[8];
    const float* ca_out_b = (const float*)d_in[9];
    const float* ff1_w    = (const float*)d_in[10];
    const float* ff1_b    = (const float*)d_in[11];
    const float* ff2_w    = (const float*)d_in[12];
    const float* ff2_b    = (const float*)d_in[13];
    const float* ln_g     = (const float*)d_in[14];
    const float* ln_b     = (const float*)d_in[15];
    const float* out_w    = (const float*)d_in[16];
    const float* out_b    = (const float*)d_in[17];
    float* out = (float*)d_out;

    const size_t QS = (size_t)NT * NB * 3 * E;   // qkv partial stride
    const size_t YS = (size_t)NT * NB * E;       // y partial stride

    float* ws = (float*)d_ws;
    float* pe       = ws;                                   // 16*E
    float* ca_const = pe + 16 * E;                          // NL*NB*E
    float* hv       = ca_const + (size_t)NL * NB * E;       // NB*E
    float* tokb     = hv + (size_t)NB * E;                  // 17*NB*E
    float* x        = tokb + (size_t)17 * NB * E;           // 16*NB*E
    float* qkv0p    = x + (size_t)16 * NB * E;              // 4 * QS
    float* qkvp     = qkv0p + 4 * QS;                       // 2 * QS
    float* attn_o   = qkvp + 2 * QS;                        // 16*NB*E
    float* ypart    = attn_o + (size_t)16 * NB * E;         // 4 * YS

    pe_init_kernel<<<16, 256, 0, stream>>>(pe);
    init_tok_kernel<<<NB, 256, 0, stream>>>(tokb, emb);

    // cross-attention constants (KV len 1 -> softmax == 1 -> V-proj only)
    for (int l = 0; l < NL; ++l) {
        const float* wv = ca_in_w + ((size_t)l * 3 * E + 2 * E) * E;
        const float* bv = ca_in_b + (size_t)l * 3 * E + 2 * E;
        gemm64x128_kernel<true><<<dim3(E / 128, 2, 1), 128, 0, stream>>>(
            cur_room, wv, bv, hv, E, E, E, 0);
        gemm64x128_kernel<true><<<dim3(E / 128, 2, 1), 128, 0, stream>>>(
            hv, ca_out_w + (size_t)l * E * E, ca_out_b + (size_t)l * E,
            ca_const + (size_t)l * NB * E, E, E, E, 0);
    }

    for (int i = 0; i < NT; ++i) {
        const int S = i + 1;
        const int M = S * NB;
        // layer-0 qkv incremental: only the new 128 rows. split-K=4.
        gemm64x128_kernel<false><<<dim3(3 * E / 128, 2, 4), 128, 0, stream>>>(
            tokb + (size_t)i * NB * E, sa_in_w, nullptr,
            qkv0p + (size_t)i * NB * 3 * E, 3 * E, E, E / 4, QS);
        for (int l = 0; l < NL; ++l) {
            const float* xin = (l == 0) ? tokb : x;
            const float* qkv_l;
            int pcount;
            if (l == 0) {
                qkv_l = qkv0p; pcount = 4;
            } else {
                gemm64x128_kernel<false><<<dim3(3 * E / 128, 2 * S, 2), 128, 0, stream>>>(
                    x, sa_in_w + (size_t)l * 3 * E * E, nullptr,
                    qkvp, 3 * E, E, E / 2, QS);
                qkv_l = qkvp; pcount = 2;
            }
            attn_kernel<<<NB * NH, 128, 0, stream>>>(
                qkv_l, QS, pcount, sa_in_b + (size_t)l * 3 * E, attn_o, S);
            gemm64x128_kernel<false><<<dim3(E / 128, 2 * S, 4), 128, 0, stream>>>(
                attn_o, sa_out_w + (size_t)l * E * E, nullptr,
                ypart, E, E, E / 4, YS);
            epilogue_kernel<<<S * 32, 256, 0, stream>>>(
                xin, ypart, YS, 4,
                sa_out_b + (size_t)l * E,
                ca_const + (size_t)l * NB * E,
                ln_g + (size_t)(l * 3 + 0) * E, ln_b + (size_t)(l * 3 + 0) * E,
                ln_g + (size_t)(l * 3 + 1) * E, ln_b + (size_t)(l * 3 + 1) * E,
                ff1_w + (size_t)l * FF * E, ff1_b + (size_t)l * FF,
                ff2_w + (size_t)l * E * FF, ff2_b + (size_t)l * E,
                ln_g + (size_t)(l * 3 + 2) * E, ln_b + (size_t)(l * 3 + 2) * E,
                x, M);
        }
        float* probs = out + 2048 + (size_t)i * NB * NV;
        gemm64x128_kernel<true><<<dim3(NV / 128, 2, 1), 128, 0, stream>>>(
            x + (size_t)(S - 1) * NB * E, out_w, out_b, probs, NV, E, E, 0);
        softmax_kernel<<<NB, 256, 0, stream>>>(
            probs, out, emb, pe + (size_t)i * E, tokb + (size_t)S * NB * E, i);
    }
}

// Round 4
// 5951.919 us; speedup vs baseline: 1.5677x; 1.4374x over previous
//
#include <hip/hip_runtime.h>
#include <math.h>

#define E  512
#define NH 8
#define HDIM 64
#define FF 32
#define NL 3
#define NV 32000
#define NB 128
#define NT 16

// ---------------------------------------------------------------- pe table
__global__ void pe_init_kernel(float* __restrict__ pe) {
    int i = blockIdx.x;  // position 0..15
    for (int e = threadIdx.x; e < E; e += blockDim.x) {
        int k = e >> 1;
        double dv = exp((double)(2 * k) * (-log(10000.0) / (double)E));
        double arg = (double)i * dv;
        pe[i * E + e] = (e & 1) ? (float)cos(arg) : (float)sin(arg);
    }
}

// ------------------------------------------------------- tok_before row 0
__global__ void init_tok_kernel(float* __restrict__ tb, const float* __restrict__ emb) {
    int b = blockIdx.x;
    for (int e = threadIdx.x; e < E; e += blockDim.x)
        tb[(size_t)b * E + e] = emb[(size_t)1 * E + e];  // SOS = 1
}

// ---------------------------------------------------------------- GEMM v3
// C_partial[z] = A[M,K-slice] @ W[N,K-slice]^T (+bias if ADD_BIAS && z==0-only use)
// Tile 64(M) x 128(N), 256 threads, 4x8 per thread. M%64==0, N%128==0, KC%16==0.
// Partial z writes to C + z*CS.
template<bool ADD_BIAS>
__global__ __launch_bounds__(256) void gemm_v3_kernel(
    const float* __restrict__ A, const float* __restrict__ W,
    const float* __restrict__ bias, float* __restrict__ C,
    int N, int K, int KC, size_t CS)
{
    __shared__ float As[16][68];    // [k][m]  (+4 pad: 2-way max)
    __shared__ float Bs[16][132];   // [k][n]
    const int tid = threadIdx.x;
    const int m0 = blockIdx.y * 64;
    const int n0 = blockIdx.x * 128;
    const int kc0 = blockIdx.z * KC;
    const int tx = tid & 15;        // N group (8 cols: tx*4 and 64+tx*4)
    const int ty = tid >> 4;        // M group (4 rows: ty*4..+3)
    const int sr = tid >> 2;        // staging row 0..63
    const int sc = (tid & 3) * 4;   // staging col 0,4,8,12

    const float* Ap  = A + (size_t)(m0 + sr) * K + kc0 + sc;
    const float* Wp0 = W + (size_t)(n0 + sr) * K + kc0 + sc;
    const float* Wp1 = W + (size_t)(n0 + 64 + sr) * K + kc0 + sc;

    float4 pa  = *(const float4*)Ap;
    float4 pb0 = *(const float4*)Wp0;
    float4 pb1 = *(const float4*)Wp1;

    float acc[4][8] = {};
    const int nkt = KC >> 4;
    for (int kt = 0; kt < nkt; ++kt) {
        __syncthreads();
        As[sc + 0][sr] = pa.x;  As[sc + 1][sr] = pa.y;
        As[sc + 2][sr] = pa.z;  As[sc + 3][sr] = pa.w;
        Bs[sc + 0][sr] = pb0.x; Bs[sc + 1][sr] = pb0.y;
        Bs[sc + 2][sr] = pb0.z; Bs[sc + 3][sr] = pb0.w;
        Bs[sc + 0][64 + sr] = pb1.x; Bs[sc + 1][64 + sr] = pb1.y;
        Bs[sc + 2][64 + sr] = pb1.z; Bs[sc + 3][64 + sr] = pb1.w;
        __syncthreads();
        if (kt + 1 < nkt) {
            const int off = 16 * (kt + 1);
            pa  = *(const float4*)(Ap + off);
            pb0 = *(const float4*)(Wp0 + off);
            pb1 = *(const float4*)(Wp1 + off);
        }
#pragma unroll
        for (int k = 0; k < 16; ++k) {
            float a[4], b[8];
            *(float4*)&a[0] = *(const float4*)&As[k][ty * 4];
            *(float4*)&b[0] = *(const float4*)&Bs[k][tx * 4];
            *(float4*)&b[4] = *(const float4*)&Bs[k][64 + tx * 4];
#pragma unroll
            for (int i = 0; i < 4; ++i)
#pragma unroll
                for (int j = 0; j < 8; ++j)
                    acc[i][j] += a[i] * b[j];
        }
    }
    float* Co = C + (size_t)blockIdx.z * CS;
#pragma unroll
    for (int i = 0; i < 4; ++i) {
        const int m = m0 + ty * 4 + i;
#pragma unroll
        for (int cj = 0; cj < 2; ++cj) {
            const int n = n0 + cj * 64 + tx * 4;
            float4 o;
            o.x = acc[i][cj * 4 + 0];
            o.y = acc[i][cj * 4 + 1];
            o.z = acc[i][cj * 4 + 2];
            o.w = acc[i][cj * 4 + 3];
            if (ADD_BIAS) {
                const float4 bv = *(const float4*)&bias[n];
                o.x += bv.x; o.y += bv.y; o.z += bv.z; o.w += bv.w;
            }
            *(float4*)&Co[(size_t)m * N + n] = o;
        }
    }
}

// ---------------- combine split-K partials: dst[i] = sum_p src[p*PS + i]
// grid*256*4 must equal n (float4 aligned).
__global__ __launch_bounds__(256) void combine4_kernel(
    const float* __restrict__ src, size_t PS, int pcount, float* __restrict__ dst)
{
    const int i = (blockIdx.x * 256 + threadIdx.x) * 4;
    float4 s = *(const float4*)&src[i];
    for (int p = 1; p < pcount; ++p) {
        const float4 a = *(const float4*)&src[(size_t)p * PS + i];
        s.x += a.x; s.y += a.y; s.z += a.z; s.w += a.w;
    }
    *(float4*)&dst[i] = s;
}

// -------------------------------------------------------- self attention
// qkv partials: qkv + p*QS, row layout [(s*NB+b)*3E + {0|E|2E} + h*64 + d].
// Sums pcount partials + bias while staging. grid = NB*NH, block = 128.
__global__ __launch_bounds__(128) void attn_kernel(
    const float* __restrict__ qkv, size_t QS, int pcount,
    const float* __restrict__ bias,   // sa_in_b + l*3E
    float* __restrict__ o, int S)
{
    const int b = blockIdx.x >> 3;
    const int h = blockIdx.x & 7;
    __shared__ float Ks[16][64];
    __shared__ float Vs[16][64];
    const int tid = threadIdx.x;
    for (int idx = tid; idx < S * 64; idx += 128) {
        int s = idx >> 6, d = idx & 63;
        size_t base = ((size_t)(s * NB + b)) * (3 * E) + h * 64 + d;
        float kk = bias[E + h * 64 + d];
        float vv = bias[2 * E + h * 64 + d];
        for (int p = 0; p < pcount; ++p) {
            kk += qkv[(size_t)p * QS + base + E];
            vv += qkv[(size_t)p * QS + base + 2 * E];
        }
        Ks[s][d] = kk;
        Vs[s][d] = vv;
    }
    __syncthreads();
    const int wid = tid >> 6, lane = tid & 63;
    const float bq = bias[h * 64 + lane];
    for (int qi = wid; qi < S; qi += 2) {
        size_t qbase = ((size_t)(qi * NB + b)) * (3 * E) + h * 64 + lane;
        float qd = bq;
        for (int p = 0; p < pcount; ++p) qd += qkv[(size_t)p * QS + qbase];
        float sc[16];
#pragma unroll
        for (int ki = 0; ki < 16; ++ki) {
            float p = 0.f;
            if (ki < S) {
                p = qd * Ks[ki][lane];
#pragma unroll
                for (int off = 32; off; off >>= 1) p += __shfl_xor(p, off);
                p *= 0.125f;  // 1/sqrt(64)
            }
            sc[ki] = p;
        }
        float m = -1e30f;
#pragma unroll
        for (int ki = 0; ki < 16; ++ki) if (ki < S) m = fmaxf(m, sc[ki]);
        float sum = 0.f;
#pragma unroll
        for (int ki = 0; ki < 16; ++ki) if (ki < S) { sc[ki] = expf(sc[ki] - m); sum += sc[ki]; }
        float inv = 1.0f / sum;
        float acc = 0.f;
#pragma unroll
        for (int ki = 0; ki < 16; ++ki) if (ki < S) acc += sc[ki] * Vs[ki][lane];
        o[((size_t)(qi * NB + b)) * E + h * 64 + lane] = acc * inv;
    }
}

// ---- fused epilogue: y = sum(ypartials)+ob; x1 = LN0(xin+y); x2 = LN1(x1+ca)
//      x = LN2(x2 + FFN(x2)).  One wave per row, 4 rows per block.
__global__ __launch_bounds__(256) void epilogue_kernel(
    const float* __restrict__ xin,
    const float* __restrict__ yp, size_t YS, int pcount,
    const float* __restrict__ ob,
    const float* __restrict__ ca,
    const float* __restrict__ g0, const float* __restrict__ b0,
    const float* __restrict__ g1, const float* __restrict__ b1,
    const float* __restrict__ w1, const float* __restrict__ b1f,
    const float* __restrict__ w2, const float* __restrict__ b2f,
    const float* __restrict__ g2, const float* __restrict__ bb2,
    float* __restrict__ xout, int rows)
{
    const int wid = threadIdx.x >> 6, lane = threadIdx.x & 63;
    const int row = blockIdx.x * 4 + wid;
    if (row >= rows) return;
    const float* xr = xin + (size_t)row * E;
    const float* cr = ca + (size_t)(row & (NB - 1)) * E;
    float v[8];
    float s = 0.f;
#pragma unroll
    for (int j = 0; j < 8; ++j) {
        int e = j * 64 + lane;
        float y = xr[e] + ob[e];
        for (int p = 0; p < pcount; ++p) y += yp[(size_t)p * YS + (size_t)row * E + e];
        v[j] = y; s += y;
    }
#pragma unroll
    for (int off = 32; off; off >>= 1) s += __shfl_xor(s, off);
    float mean = s * (1.0f / E);
    float vs = 0.f;
#pragma unroll
    for (int j = 0; j < 8; ++j) { float d = v[j] - mean; vs += d * d; }
#pragma unroll
    for (int off = 32; off; off >>= 1) vs += __shfl_xor(vs, off);
    float rstd = rsqrtf(vs * (1.0f / E) + 1e-5f);
#pragma unroll
    for (int j = 0; j < 8; ++j) {
        int e = j * 64 + lane;
        v[j] = (v[j] - mean) * rstd * g0[e] + b0[e] + cr[e];
    }
    // LN1
    s = 0.f;
#pragma unroll
    for (int j = 0; j < 8; ++j) s += v[j];
#pragma unroll
    for (int off = 32; off; off >>= 1) s += __shfl_xor(s, off);
    mean = s * (1.0f / E);
    vs = 0.f;
#pragma unroll
    for (int j = 0; j < 8; ++j) { float d = v[j] - mean; vs += d * d; }
#pragma unroll
    for (int off = 32; off; off >>= 1) vs += __shfl_xor(vs, off);
    rstd = rsqrtf(vs * (1.0f / E) + 1e-5f);
#pragma unroll
    for (int j = 0; j < 8; ++j) {
        int e = j * 64 + lane;
        v[j] = (v[j] - mean) * rstd * g1[e] + b1[e];
    }
    // FFN
    float h[FF];
#pragma unroll
    for (int f = 0; f < FF; ++f) {
        float p = 0.f;
#pragma unroll
        for (int j = 0; j < 8; ++j) p += v[j] * w1[(size_t)f * E + j * 64 + lane];
#pragma unroll
        for (int off = 32; off; off >>= 1) p += __shfl_xor(p, off);
        h[f] = fmaxf(p + b1f[f], 0.f);
    }
    float o[8];
#pragma unroll
    for (int j = 0; j < 8; ++j) {
        int e = j * 64 + lane;
        float acc = b2f[e];
#pragma unroll
        for (int f4 = 0; f4 < FF / 4; ++f4) {
            float4 w4 = *(const float4*)&w2[(size_t)e * FF + f4 * 4];
            acc += h[f4 * 4 + 0] * w4.x + h[f4 * 4 + 1] * w4.y +
                   h[f4 * 4 + 2] * w4.z + h[f4 * 4 + 3] * w4.w;
        }
        o[j] = v[j] + acc;
    }
    // LN2
    s = 0.f;
#pragma unroll
    for (int j = 0; j < 8; ++j) s += o[j];
#pragma unroll
    for (int off = 32; off; off >>= 1) s += __shfl_xor(s, off);
    mean = s * (1.0f / E);
    vs = 0.f;
#pragma unroll
    for (int j = 0; j < 8; ++j) { float d = o[j] - mean; vs += d * d; }
#pragma unroll
    for (int off = 32; off; off >>= 1) vs += __shfl_xor(vs, off);
    rstd = rsqrtf(vs * (1.0f / E) + 1e-5f);
#pragma unroll
    for (int j = 0; j < 8; ++j) {
        int e = j * 64 + lane;
        xout[(size_t)row * E + e] = (o[j] - mean) * rstd * g2[e] + bb2[e];
    }
}

// ------- softmax v2: sum 2 logit partials + bias, softmax+argmax in regs,
//         write probs, append emb[tok]+pe. One 1024-thread block per batch row.
__global__ __launch_bounds__(1024) void softmax_v2_kernel(
    const float* __restrict__ p0, const float* __restrict__ p1,
    const float* __restrict__ ob,
    float* __restrict__ probs_out, float* __restrict__ tok_out,
    const float* __restrict__ emb, const float* __restrict__ pe_row,
    float* __restrict__ tb_new, int step)
{
    const int b = blockIdx.x, t = threadIdx.x;
    const float* q0 = p0 + (size_t)b * NV;
    const float* q1 = p1 + (size_t)b * NV;
    float r[32];
    float vmax = -1e30f; int imax = 0x7fffffff;
#pragma unroll
    for (int j = 0; j < 32; ++j) {
        const int idx = j * 1024 + t;
        if (idx < NV) {
            const float v = ob[idx] + q0[idx] + q1[idx];
            r[j] = v;
            if (v > vmax) { vmax = v; imax = idx; }
        } else r[j] = -1e30f;
    }
    const int wid = t >> 6, lane = t & 63;
#pragma unroll
    for (int off = 32; off; off >>= 1) {
        const float ov = __shfl_xor(vmax, off);
        const int oi = __shfl_xor(imax, off);
        if (ov > vmax || (ov == vmax && oi < imax)) { vmax = ov; imax = oi; }
    }
    __shared__ float swv[16]; __shared__ int swi[16]; __shared__ float ssum[16];
    __shared__ float sbc[2];
    if (lane == 0) { swv[wid] = vmax; swi[wid] = imax; }
    __syncthreads();
    if (wid == 0) {
        float v = (lane < 16) ? swv[lane] : -1e30f;
        int ii = (lane < 16) ? swi[lane] : 0x7fffffff;
#pragma unroll
        for (int off = 8; off; off >>= 1) {
            const float ov = __shfl_xor(v, off);
            const int oi = __shfl_xor(ii, off);
            if (ov > v || (ov == v && oi < ii)) { v = ov; ii = oi; }
        }
        if (lane == 0) { sbc[0] = v; swi[0] = ii; }
    }
    __syncthreads();
    const float m = sbc[0];
    const int tok = swi[0];
    float psum = 0.f;
#pragma unroll
    for (int j = 0; j < 32; ++j) {
        const int idx = j * 1024 + t;
        if (idx < NV) { r[j] = expf(r[j] - m); psum += r[j]; }
    }
#pragma unroll
    for (int off = 32; off; off >>= 1) psum += __shfl_xor(psum, off);
    if (lane == 0) ssum[wid] = psum;
    __syncthreads();
    if (t == 0) {
        float s = 0.f;
        for (int w = 0; w < 16; ++w) s += ssum[w];
        sbc[1] = 1.0f / s;
    }
    __syncthreads();
    const float inv = sbc[1];
    float* P = probs_out + (size_t)b * NV;
#pragma unroll
    for (int j = 0; j < 32; ++j) {
        const int idx = j * 1024 + t;
        if (idx < NV) P[idx] = r[j] * inv;
    }
    if (t == 0) tok_out[(size_t)b * NT + step] = (float)tok;
    if (t < E) tb_new[(size_t)b * E + t] = emb[(size_t)tok * E + t] + pe_row[t];
}

// ================================================================ host
extern "C" void kernel_launch(void* const* d_in, const int* in_sizes, int n_in,
                              void* d_out, int out_size, void* d_ws, size_t ws_size,
                              hipStream_t stream) {
    const float* cur_room = (const float*)d_in[0];
    const float* emb      = (const float*)d_in[1];
    const float* sa_in_w  = (const float*)d_in[2];
    const float* sa_in_b  = (const float*)d_in[3];
    const float* sa_out_w = (const float*)d_in[4];
    const float* sa_out_b = (const float*)d_in[5];
    const float* ca_in_w  = (const float*)d_in[6];
    const float* ca_in_b  = (const float*)d_in[7];
    const float* ca_out_w = (const float*)d_in[8];
    const float* ca_out_b = (const float*)d_in[9];
    const float* ff1_w    = (const float*)d_in[10];
    const float* ff1_b    = (const float*)d_in[11];
    const float* ff2_w    = (const float*)d_in[12];
    const float* ff2_b    = (const float*)d_in[13];
    const float* ln_g     = (const float*)d_in[14];
    const float* ln_b     = (const float*)d_in[15];
    const float* out_w    = (const float*)d_in[16];
    const float* out_b    = (const float*)d_in[17];
    float* out = (float*)d_out;

    float* ws = (float*)d_ws;
    float* pe       = ws;                                   // 8K
    float* ca_const = pe + 16 * E;                          // 196K
    float* hv       = ca_const + (size_t)NL * NB * E;       // 65K
    float* tokb     = hv + (size_t)NB * E;                  // 1.11M
    float* x        = tokb + (size_t)17 * NB * E;           // 1.05M
    float* qkv0p    = x + (size_t)16 * NB * E;              // 8 * 128*1536 = 1.57M
    float* qkv0     = qkv0p + (size_t)8 * NB * 3 * E;       // 16*128*1536 = 12.6M
    float* qkvp     = qkv0 + (size_t)NT * NB * 3 * E;       // 32*128*1536 = 25.2M
    float* attn_o   = qkvp + (size_t)32 * NB * 3 * E;       // 1.05M
    float* ypart    = attn_o + (size_t)NT * NB * E;         // 64*128*512 = 4.2M
    float* vocp     = ypart + (size_t)64 * NB * E;          // 2*128*32000 = 8.2M

    pe_init_kernel<<<16, 256, 0, stream>>>(pe);
    init_tok_kernel<<<NB, 256, 0, stream>>>(tokb, emb);

    // cross-attention constants (KV len 1 -> softmax == 1 -> V-proj only)
    for (int l = 0; l < NL; ++l) {
        const float* wv = ca_in_w + ((size_t)l * 3 * E + 2 * E) * E;
        const float* bv = ca_in_b + (size_t)l * 3 * E + 2 * E;
        gemm_v3_kernel<true><<<dim3(E / 128, 2, 1), 256, 0, stream>>>(
            cur_room, wv, bv, hv, E, E, E, 0);
        gemm_v3_kernel<true><<<dim3(E / 128, 2, 1), 256, 0, stream>>>(
            hv, ca_out_w + (size_t)l * E * E, ca_out_b + (size_t)l * E,
            ca_const + (size_t)l * NB * E, E, E, E, 0);
    }

    const size_t QS0 = (size_t)NB * 3 * E;   // l0 partial stride (new rows only)

    for (int i = 0; i < NT; ++i) {
        const int S = i + 1;
        const int M = S * NB;
        // layer-0 qkv incremental: only the new 128 rows; split-K=8 + combine.
        gemm_v3_kernel<false><<<dim3(3 * E / 128, 2, 8), 256, 0, stream>>>(
            tokb + (size_t)i * NB * E, sa_in_w, nullptr,
            qkv0p, 3 * E, E, E / 8, QS0);
        combine4_kernel<<<(NB * 3 * E) / 1024, 256, 0, stream>>>(
            qkv0p, QS0, 8, qkv0 + (size_t)i * NB * 3 * E);

        const int z_qkv = (S <= 2) ? 8 : (S <= 5) ? 4 : 2;
        const int z_out = (S <= 8) ? 8 : 4;
        for (int l = 0; l < NL; ++l) {
            const float* xin = (l == 0) ? tokb : x;
            const float* qkv_l;
            size_t QS; int pcount;
            if (l == 0) {
                qkv_l = qkv0; QS = 0; pcount = 1;
            } else {
                gemm_v3_kernel<false><<<dim3(3 * E / 128, 2 * S, z_qkv), 256, 0, stream>>>(
                    x, sa_in_w + (size_t)l * 3 * E * E, nullptr,
                    qkvp, 3 * E, E, E / z_qkv, (size_t)M * 3 * E);
                qkv_l = qkvp; QS = (size_t)M * 3 * E; pcount = z_qkv;
            }
            attn_kernel<<<NB * NH, 128, 0, stream>>>(
                qkv_l, QS, pcount, sa_in_b + (size_t)l * 3 * E, attn_o, S);
            gemm_v3_kernel<false><<<dim3(E / 128, 2 * S, z_out), 256, 0, stream>>>(
                attn_o, sa_out_w + (size_t)l * E * E, nullptr,
                ypart, E, E, E / z_out, (size_t)M * E);
            epilogue_kernel<<<S * 32, 256, 0, stream>>>(
                xin, ypart, (size_t)M * E, z_out,
                sa_out_b + (size_t)l * E,
                ca_const + (size_t)l * NB * E,
                ln_g + (size_t)(l * 3 + 0) * E, ln_b + (size_t)(l * 3 + 0) * E,
                ln_g + (size_t)(l * 3 + 1) * E, ln_b + (size_t)(l * 3 + 1) * E,
                ff1_w + (size_t)l * FF * E, ff1_b + (size_t)l * FF,
                ff2_w + (size_t)l * E * FF, ff2_b + (size_t)l * E,
                ln_g + (size_t)(l * 3 + 2) * E, ln_b + (size_t)(l * 3 + 2) * E,
                x, M);
        }
        // vocab projection of last position, split-K=2; softmax consumes partials
        gemm_v3_kernel<false><<<dim3(NV / 128, 2, 2), 256, 0, stream>>>(
            x + (size_t)(S - 1) * NB * E, out_w, nullptr,
            vocp, NV, E, E / 2, (size_t)NB * NV);
        softmax_v2_kernel<<<NB, 1024, 0, stream>>>(
            vocp, vocp + (size_t)NB * NV, out_b,
            out + 2048 + (size_t)i * NB * NV, out,
            emb, pe + (size_t)i * E, tokb + (size_t)S * NB * E, i);
    }
}